// Round 7
// baseline (200.187 us; speedup 1.0000x reference)
//
#include <hip/hip_runtime.h>
#include <hip/hip_bf16.h>
#include <stdint.h>

#define BATCH 2
#define SEQ 2048
#define NHEADS 16
#define DIM 1024
#define MTOT 4096            // BATCH*SEQ
#define LOG2E 1.4426950408889634f
#define QSCALE (0.125f * LOG2E)   // d^-0.5 * log2(e), folded into Q
#define DEFER_THR 11.54f          // 8 * log2(e): defer-max threshold (exp2 domain)

typedef __attribute__((ext_vector_type(8))) short s16x8;   // 8 bf16
typedef __attribute__((ext_vector_type(4))) short s16x4;   // 4 bf16
typedef __attribute__((ext_vector_type(4))) float f32x4;
typedef unsigned short u16;

__device__ __forceinline__ u16 f2b(float f) {       // RNE (epilogues)
  union { float f; uint32_t u; } v; v.f = f;
  uint32_t r = v.u + 0x7FFFu + ((v.u >> 16) & 1u);
  return (u16)(r >> 16);
}
__device__ __forceinline__ float b2f(u16 h) {
  union { uint32_t u; float f; } v; v.u = ((uint32_t)h) << 16;
  return v.f;
}
// pack two f32 -> one u32 of 2 bf16 (lo=a, hi=b)
__device__ __forceinline__ uint32_t cvtpk_bf16(float a, float b) {
  uint32_t r;
  asm("v_cvt_pk_bf16_f32 %0, %1, %2" : "=v"(r) : "v"(a), "v"(b));
  return r;
}

// async global->LDS, 16B per lane. LDS dest must be uniform-base + lane*16.
__device__ __forceinline__ void gload_lds16(void* lds, const void* g) {
  __builtin_amdgcn_global_load_lds(
      (const __attribute__((address_space(1))) unsigned int*)g,
      (__attribute__((address_space(3))) unsigned int*)lds, 16, 0, 0);
}

// ---------------- fused prep: cast x, transpose weights, cos/sin table ----
__global__ __launch_bounds__(256) void prep_kernel(
    const float* __restrict__ x, const float* __restrict__ Wq,
    const float* __restrict__ Wk, const float* __restrict__ Wv,
    const float* __restrict__ Wo, const float* __restrict__ rot,
    u16* __restrict__ xb, u16* __restrict__ WtAll, float2* __restrict__ cs) {
  __shared__ float tile[32][33];
  int bid = blockIdx.x, t = threadIdx.x;
  if (bid < 4096) {                          // cast x -> bf16
    int i = (bid * 256 + t) * 4;
    float4 v = *(const float4*)(x + i);
    ushort4 o;
    o.x = f2b(v.x); o.y = f2b(v.y); o.z = f2b(v.z); o.w = f2b(v.w);
    *(ushort4*)(xb + i) = o;
  } else if (bid < 8192) {                   // W -> W^T bf16
    int bb = bid - 4096;
    int z = bb >> 10, xB = bb & 31, yB = (bb >> 5) & 31;
    const float* W = (z == 0) ? Wq : (z == 1) ? Wk : (z == 2) ? Wv : Wo;
    u16* Wt = WtAll + (size_t)z * DIM * DIM;
    int k0 = xB * 32, n0 = yB * 32;
    int tx = t & 31, ty = t >> 5;
#pragma unroll
    for (int i = 0; i < 4; i++) {
      int r = ty + i * 8;
      tile[r][tx] = W[(size_t)(k0 + r) * DIM + n0 + tx];
    }
    __syncthreads();
#pragma unroll
    for (int i = 0; i < 4; i++) {
      int r = ty + i * 8;
      Wt[(size_t)(n0 + r) * DIM + k0 + tx] = f2b(tile[tx][r]);
    }
  } else {                                   // cos/sin table
    int i = (bid - 8192) * 256 + t;          // SEQ*32 = 65536
    float f = rot[i];
    float s, c;
    __sincosf(f, &s, &c);
    cs[i] = make_float2(c, s);
  }
}

// ---------------- fused QKV GEMM: 256x256 tile, BK=64, 8-phase pipeline ----
#define NKT 16    // K-tiles: 1024 / 64
__global__ __launch_bounds__(512, 2) void qkv8_kernel(
    const u16* __restrict__ A, const u16* __restrict__ Bt,
    const float2* __restrict__ cs, u16* __restrict__ Qh,
    u16* __restrict__ Kh, u16* __restrict__ Vt) {
  __shared__ u16 lds[2][4][8192];   // [buf][0=A-K0,1=A-K1,2=B-K0,3=B-K1][256*32]
  const int t = threadIdx.x;
  const int w = t >> 6, l = t & 63;
  const int wr = w >> 2, wc = w & 3;          // 2 x 4 wave grid
  const int lr = l & 15, lg = l >> 4;
  const int rowBase = blockIdx.x * 256;
  const int colBase = blockIdx.y * 256;
  const char* Ab = (const char*)(A + (size_t)rowBase * DIM);
  const char* Bb = (const char*)(Bt + (size_t)colBase * DIM);
  const int t16 = t * 16;
  const int swz = ((lr >> 1) & 3) << 4;

  f32x4 acc[8][4];
#pragma unroll
  for (int m = 0; m < 8; m++)
#pragma unroll
    for (int n = 0; n < 4; n++) acc[m][n] = (f32x4){0.f, 0.f, 0.f, 0.f};

  auto stageH = [&](int buf, int kind, int kt) {
    const char* gb = (kind >= 2) ? Bb : Ab;
    int khalf = kind & 1;
    char* ldst = (char*)&lds[buf][kind][0];
#pragma unroll
    for (int i = 0; i < 2; i++) {
      int ob = t16 + i * 8192;               // 512 thr x 16B x 2 = 16KB
      int row = ob >> 6, cb = ob & 63;       // 256 rows x 64B
      gload_lds16(ldst + ob,
                  gb + (size_t)row * (DIM * 2) + kt * 128 + khalf * 64 +
                      (cb ^ (((row >> 1) & 3) << 4)));
    }
  };
  auto rdA = [&](int cur, int m, int kk) -> s16x8 {
    int R = wr * 128 + m * 16 + lr;
    return *(const s16x8*)((const char*)&lds[cur][kk][0] + R * 64 + ((lg * 16) ^ swz));
  };
  auto rdB = [&](int cur, int n, int kk) -> s16x8 {
    int R = wc * 64 + n * 16 + lr;
    return *(const s16x8*)((const char*)&lds[cur][2 + kk][0] + R * 64 + ((lg * 16) ^ swz));
  };

  // prologue: 7 halves in steady-state stream order
  stageH(0, 0, 0); stageH(0, 2, 0); stageH(0, 1, 0); stageH(0, 3, 0);
  stageH(1, 2, 1); stageH(1, 0, 1); stageH(1, 3, 1);

  for (int kt = 0; kt < NKT; ++kt) {
    const int cur = kt & 1, nxt = cur ^ 1;
    if (kt >= NKT - 2) { asm volatile("s_waitcnt vmcnt(0)" ::: "memory"); }
    else               { asm volatile("s_waitcnt vmcnt(6)" ::: "memory"); }
    __builtin_amdgcn_s_barrier();
    __builtin_amdgcn_sched_barrier(0);

    s16x8 af[4], bf[4];
    // ---- phase 0: kk0, m0-3 (+ B kk0); stage A-K1(kt+1)
#pragma unroll
    for (int i = 0; i < 4; i++) { af[i] = rdA(cur, i, 0); bf[i] = rdB(cur, i, 0); }
    if (kt + 1 < NKT) stageH(nxt, 1, kt + 1);
    __builtin_amdgcn_s_barrier();
    __builtin_amdgcn_sched_barrier(0);
    __builtin_amdgcn_s_setprio(1);
#pragma unroll
    for (int m = 0; m < 4; m++)
#pragma unroll
      for (int n = 0; n < 4; n++)
        acc[m][n] = __builtin_amdgcn_mfma_f32_16x16x32_bf16(af[m], bf[n], acc[m][n], 0, 0, 0);
    __builtin_amdgcn_s_setprio(0);
    __builtin_amdgcn_s_barrier();
    __builtin_amdgcn_sched_barrier(0);
    // ---- phase 1: kk0, m4-7; stage B-K0(kt+2)
#pragma unroll
    for (int i = 0; i < 4; i++) af[i] = rdA(cur, 4 + i, 0);
    if (kt + 2 < NKT) stageH(cur, 2, kt + 2);
    __builtin_amdgcn_s_barrier();
    __builtin_amdgcn_sched_barrier(0);
    __builtin_amdgcn_s_setprio(1);
#pragma unroll
    for (int m = 0; m < 4; m++)
#pragma unroll
      for (int n = 0; n < 4; n++)
        acc[4 + m][n] = __builtin_amdgcn_mfma_f32_16x16x32_bf16(af[m], bf[n], acc[4 + m][n], 0, 0, 0);
    __builtin_amdgcn_s_setprio(0);
    __builtin_amdgcn_s_barrier();
    __builtin_amdgcn_sched_barrier(0);
    // ---- phase 2: kk1, m0-3 (+ B kk1); stage A-K0(kt+2)
#pragma unroll
    for (int i = 0; i < 4; i++) { af[i] = rdA(cur, i, 1); bf[i] = rdB(cur, i, 1); }
    if (kt + 2 < NKT) stageH(cur, 0, kt + 2);
    __builtin_amdgcn_s_barrier();
    __builtin_amdgcn_sched_barrier(0);
    __builtin_amdgcn_s_setprio(1);
#pragma unroll
    for (int m = 0; m < 4; m++)
#pragma unroll
      for (int n = 0; n < 4; n++)
        acc[m][n] = __builtin_amdgcn_mfma_f32_16x16x32_bf16(af[m], bf[n], acc[m][n], 0, 0, 0);
    __builtin_amdgcn_s_setprio(0);
    __builtin_amdgcn_s_barrier();
    __builtin_amdgcn_sched_barrier(0);
    // ---- phase 3: kk1, m4-7; stage B-K1(kt+2)
#pragma unroll
    for (int i = 0; i < 4; i++) af[i] = rdA(cur, 4 + i, 1);
    if (kt + 2 < NKT) stageH(cur, 3, kt + 2);
    __builtin_amdgcn_s_barrier();
    __builtin_amdgcn_sched_barrier(0);
    __builtin_amdgcn_s_setprio(1);
#pragma unroll
    for (int m = 0; m < 4; m++)
#pragma unroll
      for (int n = 0; n < 4; n++)
        acc[4 + m][n] = __builtin_amdgcn_mfma_f32_16x16x32_bf16(af[m], bf[n], acc[4 + m][n], 0, 0, 0);
    __builtin_amdgcn_s_setprio(0);
    __builtin_amdgcn_s_barrier();
    __builtin_amdgcn_sched_barrier(0);
  }

  // ---- rope epilogues (per wave: one head's 64 cols) ----
  int cg = colBase + wc * 64;
  int z = cg >> 10;
  int h = (cg >> 6) & (NHEADS - 1);
  if (z == 2) {
#pragma unroll
    for (int m = 0; m < 8; m++) {
#pragma unroll
      for (int r = 0; r < 4; r++) {
        int row = rowBase + wr * 128 + m * 16 + lg * 4 + r;
        int nrow = row & (SEQ - 1);
        int b2 = row >> 11;
        const float2* csr = cs + (size_t)nrow * 32;
        float a0 = acc[m][0][r], a1 = acc[m][1][r];
        float2 f0 = csr[lr];
        float2 f1 = csr[16 + lr];
        float o0 = a0 * f0.x - a1 * f0.y;
        float o1 = a1 * f1.x + a0 * f1.y;
        size_t vbase = ((size_t)(b2 * NHEADS + h) * 64) * SEQ + nrow;
        Vt[vbase + (size_t)lr * SEQ]        = f2b(o0);
        Vt[vbase + (size_t)(16 + lr) * SEQ] = f2b(o1);
        Vt[vbase + (size_t)(32 + lr) * SEQ] = f2b(acc[m][2][r]);
        Vt[vbase + (size_t)(48 + lr) * SEQ] = f2b(acc[m][3][r]);
      }
    }
  } else {
    u16* C = (z == 0) ? Qh : Kh;
    float sc = (z == 0) ? QSCALE : 1.0f;
#pragma unroll
    for (int m = 0; m < 8; m++) {
#pragma unroll
      for (int r = 0; r < 4; r++) {
        int row = rowBase + wr * 128 + m * 16 + lg * 4 + r;
        int nrow = row & (SEQ - 1);
        int b2 = row >> 11;
        const float2* csr = cs + (size_t)nrow * 32;
        float a0 = acc[m][0][r], a1 = acc[m][1][r];
        float2 f0 = csr[lr];        // d = lr
        float2 f1 = csr[16 + lr];   // d = 16+lr
        float o0 = (a0 * f0.x - a1 * f0.y) * sc;
        float o1 = (a1 * f1.x + a0 * f1.y) * sc;
        size_t base = ((size_t)(b2 * NHEADS + h) * SEQ + nrow) * 64;
        C[base + lr]      = f2b(o0);
        C[base + 16 + lr] = f2b(o1);
        C[base + 32 + lr] = f2b(acc[m][2][r] * sc);
        C[base + 48 + lr] = f2b(acc[m][3][r] * sc);
      }
    }
  }
}

// ---------------- out-projection GEMM (64x128 tile -> 512 blocks, 2/CU) ----
__global__ __launch_bounds__(256) void gemm_out(
    const u16* __restrict__ A, const u16* __restrict__ Bt,
    float* __restrict__ C) {
  __shared__ u16 Asm[2][64 * 32];
  __shared__ u16 Bsm[2][128 * 32];
  int t = threadIdx.x;
  int w = t >> 6, l = t & 63;
  int wr = w >> 1, wc = w & 1;                // wave tile 32 x 64
  int lr = l & 15, lg = l >> 4;
  int rowBase = blockIdx.x * 64;
  int colBase = blockIdx.y * 128;
  const char* Ab = (const char*)(A + (size_t)rowBase * DIM);
  const char* Bb = (const char*)(Bt + (size_t)colBase * DIM);

  f32x4 acc[2][4];
#pragma unroll
  for (int m = 0; m < 2; m++)
#pragma unroll
    for (int n = 0; n < 4; n++) acc[m][n] = (f32x4){0.f, 0.f, 0.f, 0.f};

  auto stage = [&](int buf, int kt) {
    {
      int ob = t * 16;                        // A: 64 x 32 = 4KB
      int row = ob >> 6, cb = ob & 63;
      gload_lds16((char*)&Asm[buf][0] + ob,
                  Ab + (size_t)row * (DIM * 2) + kt * 64 + (cb ^ (((row >> 1) & 3) << 4)));
    }
#pragma unroll
    for (int i = 0; i < 2; i++) {             // B: 128 x 32 = 8KB
      int ob = t * 16 + i * 4096;
      int row = ob >> 6, cb = ob & 63;
      gload_lds16((char*)&Bsm[buf][0] + ob,
                  Bb + (size_t)row * (DIM * 2) + kt * 64 + (cb ^ (((row >> 1) & 3) << 4)));
    }
  };

  stage(0, 0);
  for (int kt = 0; kt < DIM / 32; ++kt) {
    int cur = kt & 1;
    __syncthreads();
    if (kt + 1 < DIM / 32) stage(cur ^ 1, kt + 1);
    const char* ab = (const char*)&Asm[cur][0];
    const char* bb = (const char*)&Bsm[cur][0];
    s16x8 af[2], bf[4];
#pragma unroll
    for (int m = 0; m < 2; m++) {
      int R = wr * 32 + m * 16 + lr;
      af[m] = *(const s16x8*)(ab + R * 64 + ((lg * 16) ^ (((R >> 1) & 3) << 4)));
    }
#pragma unroll
    for (int n = 0; n < 4; n++) {
      int R = wc * 64 + n * 16 + lr;
      bf[n] = *(const s16x8*)(bb + R * 64 + ((lg * 16) ^ (((R >> 1) & 3) << 4)));
    }
    __builtin_amdgcn_s_setprio(1);
#pragma unroll
    for (int m = 0; m < 2; m++)
#pragma unroll
      for (int n = 0; n < 4; n++)
        acc[m][n] = __builtin_amdgcn_mfma_f32_16x16x32_bf16(af[m], bf[n], acc[m][n], 0, 0, 0);
    __builtin_amdgcn_s_setprio(0);
  }

#pragma unroll
  for (int m = 0; m < 2; m++)
#pragma unroll
    for (int n = 0; n < 4; n++) {
      int row = rowBase + wr * 32 + m * 16 + lg * 4;
      int col = colBase + wc * 64 + n * 16 + lr;
#pragma unroll
      for (int r = 0; r < 4; r++)
        C[(size_t)(row + r) * DIM + col] = acc[m][n][r];
    }
}

// ---------------- causal flash attention (swapped-QK, register-P) --------
// 256 threads = 4 waves; wave owns 16 q-rows; block does (qt, 31-pi) pair.
// S^T = mfma(K,Q): lane holds S[q=lr][kpos=n*16+lg*4+r] -> softmax is
// per-lane scalar state; P packs (cvt_pk) straight into 16x16x16 B-frags.
__global__ __launch_bounds__(256) void attn_kernel(
    const u16* __restrict__ Qh, const u16* __restrict__ Kh,
    const u16* __restrict__ Vtg, u16* __restrict__ Ob) {
  int id = blockIdx.x;                     // 0..511
  int xcd = id & 7, within = id >> 3;      // 64 blocks per XCD
  int bh = xcd * 4 + (within >> 4);        // 4 bh per XCD
  int pi = within & 15;                    // 0..15
  int b = bh >> 4, h = bh & 15;
  __shared__ u16 Ks[2][64 * 64];
  __shared__ u16 Vs[2][64 * 64];           // [d][kpos]
  int t = threadIdx.x, w = t >> 6, l = t & 63;
  int lr = l & 15, lg = l >> 4;

  const char* Kbh = (const char*)(Kh + (size_t)bh * SEQ * 64);
  const char* Vbh = (const char*)Vtg + (size_t)bh * 64 * SEQ * 2;
  const u16* Qbh = Qh + (size_t)bh * SEQ * 64;

  auto stage = [&](int buf, int kt) {
    const char* kg = Kbh + (size_t)kt * 64 * 128;   // K rows contiguous 128B
    const char* vg = Vbh + kt * 128;                // V rows stride SEQ*2
#pragma unroll
    for (int i = 0; i < 2; i++) {
      int ob = i * 4096 + t * 16;          // 256 lanes x 16B x 2 = 8KB
      int row = ob >> 7, cb = ob & 127;
      int sw = cb ^ ((row & 7) << 4);
      gload_lds16((char*)&Ks[buf][0] + ob, kg + row * 128 + sw);
      gload_lds16((char*)&Vs[buf][0] + ob, vg + row * 4096 + sw);
    }
  };

#pragma unroll 1
  for (int ph = 0; ph < 2; ++ph) {
    int qt = ph ? (31 - pi) : pi;          // 64-row q tile index
    int nkt = qt + 1;
    int qrow = qt * 64 + w * 16 + lr;      // this lane's q row (within bh)

    s16x8 qf[2];
#pragma unroll
    for (int kk = 0; kk < 2; kk++)
      qf[kk] = *(const s16x8*)(Qbh + (size_t)qrow * 64 + kk * 32 + lg * 8);

    f32x4 o[4];                            // O^T: d = dt*16 + lg*4 + r, q = lr
#pragma unroll
    for (int dt = 0; dt < 4; dt++) o[dt] = (f32x4){0.f, 0.f, 0.f, 0.f};
    float mrun = -3.0e38f, lsum = 0.f;     // scalar per-lane (one q-row)

    __syncthreads();                       // prior phase LDS reads fully done
    stage(0, 0);
    for (int kt = 0; kt < nkt; ++kt) {
      int cur = kt & 1;
      __syncthreads();                     // drains vmcnt: buf cur staged
      if (kt + 1 < nkt) stage(cur ^ 1, kt + 1);
      const char* kb = (const char*)&Ks[cur][0];
      const char* vb = (const char*)&Vs[cur][0];

      // S^T = K Q^T (scale+log2e folded into Q)
      f32x4 s[4];
#pragma unroll
      for (int n = 0; n < 4; n++) s[n] = (f32x4){0.f, 0.f, 0.f, 0.f};
      __builtin_amdgcn_s_setprio(1);
#pragma unroll
      for (int n = 0; n < 4; n++)
#pragma unroll
        for (int kk = 0; kk < 2; kk++) {
          int R = n * 16 + lr;             // kpos row
          s16x8 kf = *(const s16x8*)(kb + R * 128 + ((kk * 64 + lg * 16) ^ ((R & 7) << 4)));
          s[n] = __builtin_amdgcn_mfma_f32_16x16x32_bf16(kf, qf[kk], s[n], 0, 0, 0);
        }
      __builtin_amdgcn_s_setprio(0);

      if (kt == nkt - 1) {                 // causal mask (diagonal tile)
#pragma unroll
        for (int n = 0; n < 4; n++) {
          int kbase = kt * 64 + n * 16 + lg * 4;
#pragma unroll
          for (int r = 0; r < 4; r++)
            if (kbase + r > qrow) s[n][r] = -3.0e38f;
        }
      }

      // per-lane online softmax (q-row spread over 4 lg-lanes)
      float mloc;
      {
        float m0 = fmaxf(fmaxf(s[0][0], s[0][1]), fmaxf(s[0][2], s[0][3]));
        float m1 = fmaxf(fmaxf(s[1][0], s[1][1]), fmaxf(s[1][2], s[1][3]));
        float m2 = fmaxf(fmaxf(s[2][0], s[2][1]), fmaxf(s[2][2], s[2][3]));
        float m3 = fmaxf(fmaxf(s[3][0], s[3][1]), fmaxf(s[3][2], s[3][3]));
        mloc = fmaxf(fmaxf(m0, m1), fmaxf(m2, m3));
      }
      mloc = fmaxf(mloc, __shfl_xor(mloc, 16, 64));
      mloc = fmaxf(mloc, __shfl_xor(mloc, 32, 64));   // row max
      if (!__all(mloc - mrun <= DEFER_THR)) {         // rare rescale
        float mn = fmaxf(mrun, mloc);
        float alpha = exp2f(mrun - mn);
        mrun = mn; lsum *= alpha;
#pragma unroll
        for (int dt = 0; dt < 4; dt++)
#pragma unroll
          for (int r = 0; r < 4; r++) o[dt][r] *= alpha;
      }
      float p[4][4];
#pragma unroll
      for (int n = 0; n < 4; n++)
#pragma unroll
        for (int r = 0; r < 4; r++) p[n][r] = exp2f(s[n][r] - mrun);
      lsum += ((p[0][0] + p[0][1]) + (p[0][2] + p[0][3])) +
              ((p[1][0] + p[1][1]) + (p[1][2] + p[1][3])) +
              ((p[2][0] + p[2][1]) + (p[2][2] + p[2][3])) +
              ((p[3][0] + p[3][1]) + (p[3][2] + p[3][3]));

      // pack P rows into 16x16x16 B-fragments (k = lg*4 + j), zero exchange
      s16x4 pb[4];
#pragma unroll
      for (int n = 0; n < 4; n++) {
        union { uint32_t u[2]; s16x4 v; } pu;
        pu.u[0] = cvtpk_bf16(p[n][0], p[n][1]);
        pu.u[1] = cvtpk_bf16(p[n][2], p[n][3]);
        pb[n] = pu.v;
      }

      // O^T += V^T P^T : A-frag = Vs[d][kpos] 8B reads
      __builtin_amdgcn_s_setprio(1);
#pragma unroll
      for (int dt = 0; dt < 4; dt++) {
        int R = dt * 16 + lr;              // d row
#pragma unroll
        for (int n = 0; n < 4; n++) {
          s16x4 vf = *(const s16x4*)(vb + R * 128 + ((n * 32 + lg * 8) ^ ((R & 7) << 4)));
          o[dt] = __builtin_amdgcn_mfma_f32_16x16x16bf16_1k(vf, pb[n], o[dt], 0, 0, 0);
        }
      }
      __builtin_amdgcn_s_setprio(0);
    }

    // finalize: row sum over the 4 lg-lanes, normalize, one row per lane
    float sum = lsum;
    sum += __shfl_xor(sum, 16, 64);
    sum += __shfl_xor(sum, 32, 64);
    float inv = 1.0f / sum;
    u16* orow = Ob + ((size_t)b * SEQ + qrow) * DIM + h * 64 + lg * 4;
#pragma unroll
    for (int dt = 0; dt < 4; dt++) {
      ushort4 ov;
      ov.x = f2b(o[dt][0] * inv); ov.y = f2b(o[dt][1] * inv);
      ov.z = f2b(o[dt][2] * inv); ov.w = f2b(o[dt][3] * inv);
      *(ushort4*)(orow + dt * 16) = ov;
    }
  }
}

// ---------------- launch ----------------
extern "C" void kernel_launch(void* const* d_in, const int* in_sizes, int n_in,
                              void* d_out, int out_size, void* d_ws, size_t ws_size,
                              hipStream_t stream) {
  (void)in_sizes; (void)n_in; (void)out_size; (void)ws_size;
  const float* x = (const float*)d_in[0];
  const float* rot = (const float*)d_in[1];
  const float* Wq = (const float*)d_in[2];
  const float* Wk = (const float*)d_in[3];
  const float* Wv = (const float*)d_in[4];
  const float* Wo = (const float*)d_in[5];

  char* ws = (char*)d_ws;
  u16* xb    = (u16*)(ws);                         // 8 MB
  u16* WtAll = (u16*)(ws + (8ll << 20));           // 8 MB
  u16* Qh    = (u16*)(ws + (16ll << 20));          // 8 MB
  u16* Kh    = (u16*)(ws + (24ll << 20));          // 8 MB
  u16* Vt    = (u16*)(ws + (32ll << 20));          // 8 MB
  u16* Ob    = (u16*)(ws + (40ll << 20));          // 8 MB
  float2* cs = (float2*)(ws + (48ll << 20));       // 0.5 MB

  prep_kernel<<<8448, 256, 0, stream>>>(x, Wq, Wk, Wv, Wo, rot, xb, WtAll, cs);
  qkv8_kernel<<<dim3(16, 12), 512, 0, stream>>>(xb, WtAll, cs, Qh, Kh, Vt);
  attn_kernel<<<512, 256, 0, stream>>>(Qh, Kh, Vt, Ob);
  gemm_out<<<dim3(64, 8), 256, 0, stream>>>(Ob, WtAll + 3ll * DIM * DIM, (float*)d_out);
}